// Round 5
// baseline (246.943 us; speedup 1.0000x reference)
//
#include <hip/hip_runtime.h>

// Steered 3x3 conv as per-pixel GEMM (K=256 = 64ch x 4 feats) via bf16 MFMA.
// v5: CHCH 16->8 (LDS 51.2->25.6 KB) so 6 blocks/CU fit and all 1024 blocks
// are co-resident (zero tail). 8-chunk 2-phase async global_load_lds pipeline,
// TILE_H=8 with shared tap rows, bijective XCD swizzle.
// B-frag: lane l -> col = l&31 (pixel), k = 16*kc + 8*(l>>5) + r  (verified r2)
// C/D:    col = lane&31, row(o) = (r&3) + 8*(r>>2) + 4*(lane>>5)  (verified r2)

typedef __bf16 bf16x8 __attribute__((ext_vector_type(8)));
typedef float  f32x16 __attribute__((ext_vector_type(16)));
typedef unsigned int u32;
typedef const __attribute__((address_space(1))) u32* gp_t;
typedef __attribute__((address_space(3))) u32* lp_t;

#define HH 128
#define WW 128
#define TILE_H 8
#define TILE_W 32
#define CHCH 8             // channels per chunk
#define NCHUNK 8
#define RROWS 10           // TILE_H + 2
#define RCOLS 40           // staged cols: gw = w0-4 .. w0+35 (16B aligned)
#define CHF (RROWS * RCOLS) // 400 floats per channel
#define CHIMG 65536         // bytes per (n,ch) image plane

__global__ void wt_to_bf16(const float* __restrict__ wt,
                           unsigned short* __restrict__ wb) {
    int i = blockIdx.x * 256 + threadIdx.x;
    union { float f; u32 u; } v; v.f = wt[i];
    wb[i] = (unsigned short)((v.u + 0x7FFF + ((v.u >> 16) & 1)) >> 16);
}

__global__ __launch_bounds__(256, 6) void steered_conv_mfma(
    const float* __restrict__ x, const float* __restrict__ theta,
    const unsigned short* __restrict__ wb, const float* __restrict__ bias,
    float* __restrict__ out)
{
    __shared__ float lds[2][CHCH][CHF];   // 25600 B -> 6 blocks/CU

    const int tid  = threadIdx.x;
    const int wid  = tid >> 6, lane = tid & 63;
    const int pc   = lane & 31, hx = lane >> 5;

    // bijective XCD swizzle: 1024 blocks, 128/XCD = 2 whole images
    const int bb  = blockIdx.x;
    const int swz = (bb & 7) * 128 + (bb >> 3);
    const int n  = swz >> 6;
    const int ty = (swz >> 2) & 15;
    const int tx = swz & 3;
    const int h0 = ty * TILE_H, w0 = tx * TILE_W;
    const int p0 = wid * 2;               // this wave's 2 pixel rows

    // ---- per-lane DMA constants: instr A covers ch bytes [0,1024),
    //      instr B covers [1024,1600) with 36 active lanes ----
    const int oA = lane * 16;
    const int rA = oA / 160;
    const int cA = oA - rA * 160;
    int ghA = h0 - 1 + rA; ghA = ghA < 0 ? 0 : (ghA > 127 ? 127 : ghA);
    int srcA = ghA * 512 + w0 * 4 - 16 + cA;
    srcA = srcA < 0 ? 0 : srcA;
    const bool skA = (w0 == 0 && cA < 16) || (w0 == 96 && cA >= 144);

    const int oB = 1024 + lane * 16;
    const int rB = oB / 160;
    const int cB = oB - rB * 160;
    int ghB = h0 - 1 + rB; ghB = ghB < 0 ? 0 : (ghB > 127 ? 127 : ghB);
    int srcB = ghB * 512 + w0 * 4 - 16 + cB;
    srcB = srcB < 0 ? 0 : (srcB > CHIMG - 16 ? CHIMG - 16 : srcB);
    const bool skB = (lane >= 36) || (w0 == 0 && cB < 16) || (w0 == 96 && cB >= 144);

    const char* xn = (const char*)x + (size_t)n * 64 * CHIMG;
    const bool boundary = (h0 == 0) | (h0 == 120) | (w0 == 0) | (w0 == 96);

    // ---- stage chunk 0 (async DMA; drained by first __syncthreads) ----
    #pragma unroll
    for (int j = 0; j < 2; ++j) {
        const int ch = wid * 2 + j;
        const char* s = xn + ch * CHIMG;
        char* d = (char*)&lds[0][ch][0];
        if (!skA) __builtin_amdgcn_global_load_lds((gp_t)(s + srcA), (lp_t)d, 16, 0, 0);
        if (!skB) __builtin_amdgcn_global_load_lds((gp_t)(s + srcB), (lp_t)(d + 1024), 16, 0, 0);
    }

    // ---- per-pixel harmonics for the wave's two rows ----
    const int wg = w0 + pc;
    const float thA = theta[(n * HH + h0 + p0) * WW + wg];
    const float thB = theta[(n * HH + h0 + p0 + 1) * WW + wg];
    float s1a, c1a, s1b, c1b;
    __sincosf(6.2831853071795864769f * thA, &s1a, &c1a);
    __sincosf(6.2831853071795864769f * thB, &s1b, &c1b);
    const float c2a = 2.f * c1a * c1a - 1.f, s2a = 2.f * s1a * c1a;
    const float c2b = 2.f * c1b * c1b - 1.f, s2b = 2.f * s1b * c1b;

    f32x16 acc00, acc01, acc10, acc11;
    #pragma unroll
    for (int r = 0; r < 16; ++r) { acc00[r]=0.f; acc01[r]=0.f; acc10[r]=0.f; acc11[r]=0.f; }

    const float RS  = 0.35355339059327373f;   // sqrt(2)/4
    const float HMR = 0.14644660940672627f;   // 0.5 - RS

    #pragma unroll 1
    for (int c = 0; c < NCHUNK; ++c) {
        __syncthreads();   // implicit vmcnt(0): chunk c landed; WAR-safe
        if (boundary) {
            float* bz = &lds[c & 1][0][0];
            if (h0 == 0)
                for (int i = tid; i < CHCH * RCOLS; i += 256) bz[(i / RCOLS) * CHF + (i % RCOLS)] = 0.f;
            if (h0 == 120)
                for (int i = tid; i < CHCH * RCOLS; i += 256) bz[(i / RCOLS) * CHF + 9 * RCOLS + (i % RCOLS)] = 0.f;
            if (w0 == 0)
                for (int i = tid; i < CHCH * RROWS; i += 256) bz[(i / RROWS) * CHF + (i % RROWS) * RCOLS + 3] = 0.f;
            if (w0 == 96)
                for (int i = tid; i < CHCH * RROWS; i += 256) bz[(i / RROWS) * CHF + (i % RROWS) * RCOLS + 36] = 0.f;
            __syncthreads();
        }
        if (c < NCHUNK - 1) {   // issue next chunk's DMA; overlaps compute(c)
            const char* xc = xn + (size_t)(c + 1) * CHCH * CHIMG;
            #pragma unroll
            for (int j = 0; j < 2; ++j) {
                const int ch = wid * 2 + j;
                const char* s = xc + ch * CHIMG;
                char* d = (char*)&lds[(c + 1) & 1][ch][0];
                if (!skA) __builtin_amdgcn_global_load_lds((gp_t)(s + srcA), (lp_t)d, 16, 0, 0);
                if (!skB) __builtin_amdgcn_global_load_lds((gp_t)(s + srcB), (lp_t)(d + 1024), 16, 0, 0);
            }
        }
        // ---- compute chunk c: 2 K-steps of 16 (4 channels each) ----
        const float* tb = &lds[c & 1][0][p0 * RCOLS + pc + 3];
        const unsigned short* wk = wb + pc * 256 + c * 32 + hx * 8;
        #pragma unroll
        for (int kc = 0; kc < 2; ++kc) {
            bf16x8 b0, b1;
            #pragma unroll
            for (int cs = 0; cs < 2; ++cs) {
                const float* t = tb + (kc * 4 + hx * 2 + cs) * CHF;
                const float t00=t[0],   t01=t[1],   t02=t[2];
                const float t10=t[40],  t11=t[41],  t12=t[42];
                const float t20=t[80],  t21=t[81],  t22=t[82];
                const float t30=t[120], t31=t[121], t32=t[122];
                const float S0=t00+t01+t02, S1=t10+t11+t12;
                const float S2=t20+t21+t22, S3=t30+t31+t32;
                const float D0=t02-t00, D1=t12-t10, D2=t22-t20, D3=t32-t30;
                {   // pixel row p0 (staged rows 0,1,2)
                    const float F1 = RS * (S0 + S2 + S1 - t11);
                    const float B2 = RS * (D0 + D2) + 0.5f * D1;
                    const float B3 = RS * (S2 - S0) + HMR * (t21 - t01);
                    const float B4 = 0.5f * (S1 - t11 - t01 - t21);
                    const float B5 = 0.5f * (D2 - D0);
                    b0[cs*4+0] = (__bf16)t11;
                    b0[cs*4+1] = (__bf16)F1;
                    b0[cs*4+2] = (__bf16)(c1a * B2 + s1a * B3);
                    b0[cs*4+3] = (__bf16)(c2a * B4 + s2a * B5);
                }
                {   // pixel row p0+1 (staged rows 1,2,3)
                    const float F1 = RS * (S1 + S3 + S2 - t21);
                    const float B2 = RS * (D1 + D3) + 0.5f * D2;
                    const float B3 = RS * (S3 - S1) + HMR * (t31 - t11);
                    const float B4 = 0.5f * (S2 - t21 - t11 - t31);
                    const float B5 = 0.5f * (D3 - D1);
                    b1[cs*4+0] = (__bf16)t21;
                    b1[cs*4+1] = (__bf16)F1;
                    b1[cs*4+2] = (__bf16)(c1b * B2 + s1b * B3);
                    b1[cs*4+3] = (__bf16)(c2b * B4 + s2b * B5);
                }
            }
            const unsigned short* wr = wk + kc * 16;
            const bf16x8 A0 = *(const bf16x8*)wr;
            const bf16x8 A1 = *(const bf16x8*)(wr + 32 * 256);
            acc00 = __builtin_amdgcn_mfma_f32_32x32x16_bf16(A0, b0, acc00, 0, 0, 0);
            acc01 = __builtin_amdgcn_mfma_f32_32x32x16_bf16(A1, b0, acc01, 0, 0, 0);
            acc10 = __builtin_amdgcn_mfma_f32_32x32x16_bf16(A0, b1, acc10, 0, 0, 0);
            acc11 = __builtin_amdgcn_mfma_f32_32x32x16_bf16(A1, b1, acc11, 0, 0, 0);
        }
    }

    const size_t hw = (size_t)HH * WW;
    float* op = out + (size_t)n * 64 * hw + (size_t)(h0 + p0) * WW + w0 + pc;
    #pragma unroll
    for (int r = 0; r < 16; ++r) {
        const int o  = (r & 3) + 8 * (r >> 2) + 4 * hx;
        const float bo = bias[o], bo2 = bias[o + 32];
        op[(size_t)o * hw]             = acc00[r] + bo;
        op[(size_t)(o + 32) * hw]      = acc01[r] + bo2;
        op[(size_t)o * hw + WW]        = acc10[r] + bo;
        op[(size_t)(o + 32) * hw + WW] = acc11[r] + bo2;
    }
}

extern "C" void kernel_launch(void* const* d_in, const int* in_sizes, int n_in,
                              void* d_out, int out_size, void* d_ws, size_t ws_size,
                              hipStream_t stream) {
    const float* x     = (const float*)d_in[0];
    const float* theta = (const float*)d_in[1];
    const float* wt    = (const float*)d_in[2];
    const float* bias  = (const float*)d_in[3];
    float* out = (float*)d_out;
    unsigned short* wb = (unsigned short*)d_ws;   // 32 KB bf16 weights

    wt_to_bf16<<<64, 256, 0, stream>>>(wt, wb);

    steered_conv_mfma<<<1024, 256, 0, stream>>>(x, theta, wb, bias, out);
}

// Round 6
// 42.921 us; speedup vs baseline: 5.7534x; 5.7534x over previous
//
#include <hip/hip_runtime.h>

// Steered 3x3 conv as per-pixel GEMM (K=256 = 64ch x 4 feats) via bf16 MFMA.
// v6: v5 with the occupancy bound FIXED: launch_bounds(256,4) (not 6 -- the
// 4x f32x16 accumulators need 64 VGPRs; a 6-wave/EU cap forced spill-to-
// scratch: WRITE_SIZE 65->807MB, 7x regression). 25.6 KB LDS, 4 blocks/CU,
// grid 1024 = 256CU x 4 -> all blocks co-resident, zero tail.
// B-frag: lane l -> col = l&31 (pixel), k = 16*kc + 8*(l>>5) + r  (verified r2)
// C/D:    col = lane&31, row(o) = (r&3) + 8*(r>>2) + 4*(lane>>5)  (verified r2)

typedef __bf16 bf16x8 __attribute__((ext_vector_type(8)));
typedef float  f32x16 __attribute__((ext_vector_type(16)));
typedef unsigned int u32;
typedef const __attribute__((address_space(1))) u32* gp_t;
typedef __attribute__((address_space(3))) u32* lp_t;

#define HH 128
#define WW 128
#define TILE_H 8
#define TILE_W 32
#define CHCH 8             // channels per chunk
#define NCHUNK 8
#define RROWS 10           // TILE_H + 2
#define RCOLS 40           // staged cols: gw = w0-4 .. w0+35 (16B aligned)
#define CHF (RROWS * RCOLS) // 400 floats per channel
#define CHIMG 65536         // bytes per (n,ch) image plane

__global__ void wt_to_bf16(const float* __restrict__ wt,
                           unsigned short* __restrict__ wb) {
    int i = blockIdx.x * 256 + threadIdx.x;
    union { float f; u32 u; } v; v.f = wt[i];
    wb[i] = (unsigned short)((v.u + 0x7FFF + ((v.u >> 16) & 1)) >> 16);
}

__global__ __launch_bounds__(256, 4) void steered_conv_mfma(
    const float* __restrict__ x, const float* __restrict__ theta,
    const unsigned short* __restrict__ wb, const float* __restrict__ bias,
    float* __restrict__ out)
{
    __shared__ float lds[2][CHCH][CHF];   // 25600 B

    const int tid  = threadIdx.x;
    const int wid  = tid >> 6, lane = tid & 63;
    const int pc   = lane & 31, hx = lane >> 5;

    // bijective XCD swizzle: 1024 blocks, 128/XCD = 2 whole images
    const int bb  = blockIdx.x;
    const int swz = (bb & 7) * 128 + (bb >> 3);
    const int n  = swz >> 6;
    const int ty = (swz >> 2) & 15;
    const int tx = swz & 3;
    const int h0 = ty * TILE_H, w0 = tx * TILE_W;
    const int p0 = wid * 2;               // this wave's 2 pixel rows

    // ---- per-lane DMA constants: instr A covers ch bytes [0,1024),
    //      instr B covers [1024,1600) with 36 active lanes ----
    const int oA = lane * 16;
    const int rA = oA / 160;
    const int cA = oA - rA * 160;
    int ghA = h0 - 1 + rA; ghA = ghA < 0 ? 0 : (ghA > 127 ? 127 : ghA);
    int srcA = ghA * 512 + w0 * 4 - 16 + cA;
    srcA = srcA < 0 ? 0 : srcA;
    const bool skA = (w0 == 0 && cA < 16) || (w0 == 96 && cA >= 144);

    const int oB = 1024 + lane * 16;
    const int rB = oB / 160;
    const int cB = oB - rB * 160;
    int ghB = h0 - 1 + rB; ghB = ghB < 0 ? 0 : (ghB > 127 ? 127 : ghB);
    int srcB = ghB * 512 + w0 * 4 - 16 + cB;
    srcB = srcB < 0 ? 0 : (srcB > CHIMG - 16 ? CHIMG - 16 : srcB);
    const bool skB = (lane >= 36) || (w0 == 0 && cB < 16) || (w0 == 96 && cB >= 144);

    const char* xn = (const char*)x + (size_t)n * 64 * CHIMG;
    const bool boundary = (h0 == 0) | (h0 == 120) | (w0 == 0) | (w0 == 96);

    // ---- stage chunk 0 (async DMA; drained by first __syncthreads) ----
    #pragma unroll
    for (int j = 0; j < 2; ++j) {
        const int ch = wid * 2 + j;
        const char* s = xn + ch * CHIMG;
        char* d = (char*)&lds[0][ch][0];
        if (!skA) __builtin_amdgcn_global_load_lds((gp_t)(s + srcA), (lp_t)d, 16, 0, 0);
        if (!skB) __builtin_amdgcn_global_load_lds((gp_t)(s + srcB), (lp_t)(d + 1024), 16, 0, 0);
    }

    // ---- per-pixel harmonics for the wave's two rows ----
    const int wg = w0 + pc;
    const float thA = theta[(n * HH + h0 + p0) * WW + wg];
    const float thB = theta[(n * HH + h0 + p0 + 1) * WW + wg];
    float s1a, c1a, s1b, c1b;
    __sincosf(6.2831853071795864769f * thA, &s1a, &c1a);
    __sincosf(6.2831853071795864769f * thB, &s1b, &c1b);
    const float c2a = 2.f * c1a * c1a - 1.f, s2a = 2.f * s1a * c1a;
    const float c2b = 2.f * c1b * c1b - 1.f, s2b = 2.f * s1b * c1b;

    f32x16 acc00, acc01, acc10, acc11;
    #pragma unroll
    for (int r = 0; r < 16; ++r) { acc00[r]=0.f; acc01[r]=0.f; acc10[r]=0.f; acc11[r]=0.f; }

    const float RS  = 0.35355339059327373f;   // sqrt(2)/4
    const float HMR = 0.14644660940672627f;   // 0.5 - RS

    #pragma unroll 1
    for (int c = 0; c < NCHUNK; ++c) {
        __syncthreads();   // implicit vmcnt(0): chunk c landed; WAR-safe
        if (boundary) {
            float* bz = &lds[c & 1][0][0];
            if (h0 == 0)
                for (int i = tid; i < CHCH * RCOLS; i += 256) bz[(i / RCOLS) * CHF + (i % RCOLS)] = 0.f;
            if (h0 == 120)
                for (int i = tid; i < CHCH * RCOLS; i += 256) bz[(i / RCOLS) * CHF + 9 * RCOLS + (i % RCOLS)] = 0.f;
            if (w0 == 0)
                for (int i = tid; i < CHCH * RROWS; i += 256) bz[(i / RROWS) * CHF + (i % RROWS) * RCOLS + 3] = 0.f;
            if (w0 == 96)
                for (int i = tid; i < CHCH * RROWS; i += 256) bz[(i / RROWS) * CHF + (i % RROWS) * RCOLS + 36] = 0.f;
            __syncthreads();
        }
        if (c < NCHUNK - 1) {   // issue next chunk's DMA; overlaps compute(c)
            const char* xc = xn + (size_t)(c + 1) * CHCH * CHIMG;
            #pragma unroll
            for (int j = 0; j < 2; ++j) {
                const int ch = wid * 2 + j;
                const char* s = xc + ch * CHIMG;
                char* d = (char*)&lds[(c + 1) & 1][ch][0];
                if (!skA) __builtin_amdgcn_global_load_lds((gp_t)(s + srcA), (lp_t)d, 16, 0, 0);
                if (!skB) __builtin_amdgcn_global_load_lds((gp_t)(s + srcB), (lp_t)(d + 1024), 16, 0, 0);
            }
        }
        // ---- compute chunk c: 2 K-steps of 16 (4 channels each) ----
        const float* tb = &lds[c & 1][0][p0 * RCOLS + pc + 3];
        const unsigned short* wk = wb + pc * 256 + c * 32 + hx * 8;
        #pragma unroll
        for (int kc = 0; kc < 2; ++kc) {
            bf16x8 b0, b1;
            #pragma unroll
            for (int cs = 0; cs < 2; ++cs) {
                const float* t = tb + (kc * 4 + hx * 2 + cs) * CHF;
                const float t00=t[0],   t01=t[1],   t02=t[2];
                const float t10=t[40],  t11=t[41],  t12=t[42];
                const float t20=t[80],  t21=t[81],  t22=t[82];
                const float t30=t[120], t31=t[121], t32=t[122];
                const float S0=t00+t01+t02, S1=t10+t11+t12;
                const float S2=t20+t21+t22, S3=t30+t31+t32;
                const float D0=t02-t00, D1=t12-t10, D2=t22-t20, D3=t32-t30;
                {   // pixel row p0 (staged rows 0,1,2)
                    const float F1 = RS * (S0 + S2 + S1 - t11);
                    const float B2 = RS * (D0 + D2) + 0.5f * D1;
                    const float B3 = RS * (S2 - S0) + HMR * (t21 - t01);
                    const float B4 = 0.5f * (S1 - t11 - t01 - t21);
                    const float B5 = 0.5f * (D2 - D0);
                    b0[cs*4+0] = (__bf16)t11;
                    b0[cs*4+1] = (__bf16)F1;
                    b0[cs*4+2] = (__bf16)(c1a * B2 + s1a * B3);
                    b0[cs*4+3] = (__bf16)(c2a * B4 + s2a * B5);
                }
                {   // pixel row p0+1 (staged rows 1,2,3)
                    const float F1 = RS * (S1 + S3 + S2 - t21);
                    const float B2 = RS * (D1 + D3) + 0.5f * D2;
                    const float B3 = RS * (S3 - S1) + HMR * (t31 - t11);
                    const float B4 = 0.5f * (S2 - t21 - t11 - t31);
                    const float B5 = 0.5f * (D3 - D1);
                    b1[cs*4+0] = (__bf16)t21;
                    b1[cs*4+1] = (__bf16)F1;
                    b1[cs*4+2] = (__bf16)(c1b * B2 + s1b * B3);
                    b1[cs*4+3] = (__bf16)(c2b * B4 + s2b * B5);
                }
            }
            const unsigned short* wr = wk + kc * 16;
            const bf16x8 A0 = *(const bf16x8*)wr;
            const bf16x8 A1 = *(const bf16x8*)(wr + 32 * 256);
            acc00 = __builtin_amdgcn_mfma_f32_32x32x16_bf16(A0, b0, acc00, 0, 0, 0);
            acc01 = __builtin_amdgcn_mfma_f32_32x32x16_bf16(A1, b0, acc01, 0, 0, 0);
            acc10 = __builtin_amdgcn_mfma_f32_32x32x16_bf16(A0, b1, acc10, 0, 0, 0);
            acc11 = __builtin_amdgcn_mfma_f32_32x32x16_bf16(A1, b1, acc11, 0, 0, 0);
        }
    }

    const size_t hw = (size_t)HH * WW;
    float* op = out + (size_t)n * 64 * hw + (size_t)(h0 + p0) * WW + w0 + pc;
    #pragma unroll
    for (int r = 0; r < 16; ++r) {
        const int o  = (r & 3) + 8 * (r >> 2) + 4 * hx;
        const float bo = bias[o], bo2 = bias[o + 32];
        op[(size_t)o * hw]             = acc00[r] + bo;
        op[(size_t)(o + 32) * hw]      = acc01[r] + bo2;
        op[(size_t)o * hw + WW]        = acc10[r] + bo;
        op[(size_t)(o + 32) * hw + WW] = acc11[r] + bo2;
    }
}

extern "C" void kernel_launch(void* const* d_in, const int* in_sizes, int n_in,
                              void* d_out, int out_size, void* d_ws, size_t ws_size,
                              hipStream_t stream) {
    const float* x     = (const float*)d_in[0];
    const float* theta = (const float*)d_in[1];
    const float* wt    = (const float*)d_in[2];
    const float* bias  = (const float*)d_in[3];
    float* out = (float*)d_out;
    unsigned short* wb = (unsigned short*)d_ws;   // 32 KB bf16 weights

    wt_to_bf16<<<64, 256, 0, stream>>>(wt, wb);

    steered_conv_mfma<<<1024, 256, 0, stream>>>(x, theta, wb, bias, out);
}